// Round 21
// baseline (2885.016 us; speedup 1.0000x reference)
//
#include <hip/hip_runtime.h>

#define B_DIM 64
#define T_DIM 2048
#define F_DIM 512
#define H_DIM 128
#define G_DIM 384  // 3*H

typedef _Float16 half2_t __attribute__((ext_vector_type(2)));
typedef _Float16 f16x8   __attribute__((ext_vector_type(8)));
typedef unsigned int uint32;
typedef uint32 u32x4 __attribute__((ext_vector_type(4)));
typedef short bf16x8 __attribute__((ext_vector_type(8)));
typedef float f32x4  __attribute__((ext_vector_type(4)));

__device__ __forceinline__ float sigmoid_f(float x) {
    return __fdividef(1.0f, 1.0f + __expf(-x));
}
__device__ __forceinline__ float tanh_f(float x) {
    return __fdividef(2.0f, 1.0f + __expf(-2.0f * x)) - 1.0f;
}

__device__ __forceinline__ uint32 packf16(float a, float b) {
    half2_t p; p.x = (_Float16)a; p.y = (_Float16)b;
    return __builtin_bit_cast(uint32, p);
}

__device__ __forceinline__ uint32 pk_bf16(float lo, float hi) {
    uint32 r;
    asm("v_cvt_pk_bf16_f32 %0, %1, %2" : "=v"(r) : "v"(lo), "v"(hi));
    return r;
}

#define FAST_BARRIER()                                                            \
    __builtin_amdgcn_sched_barrier(0);                                            \
    asm volatile("s_waitcnt lgkmcnt(0)" ::: "memory");                            \
    __builtin_amdgcn_s_barrier();                                                 \
    __builtin_amdgcn_sched_barrier(0);

// ---------------------------------------------------------------------------
// bf16 MFMA GEMM (R10-proven; R17-best config uses this for proj and gx0).
// ---------------------------------------------------------------------------
template<int KDIM, int NDIM, bool DO_LEN>
__global__ __launch_bounds__(256)
void gemm_mfma_kernel(const float* __restrict__ A, const float* __restrict__ W,
                      const float* __restrict__ bias, float* __restrict__ C,
                      int* __restrict__ lengths)
{
    constexpr int KSTEPS = KDIM / 32;
    constexpr int PAD = 40;
    __shared__ __align__(16) unsigned short At[128 * PAD];
    __shared__ __align__(16) unsigned short Bt[128 * PAD];

    const int tid = threadIdx.x;
    const int m0  = blockIdx.x * 128;
    const int n0  = blockIdx.y * 128;
    const int row = tid >> 1;
    const int kh  = tid & 1;

    const float* Ap = A + (size_t)(m0 + row) * KDIM + kh * 16;
    const float* Wp = W + (size_t)(n0 + row) * KDIM + kh * 16;

    float4 aPre[4], bPre[4];
#pragma unroll
    for (int q = 0; q < 4; ++q) {
        aPre[q] = *(const float4*)(Ap + q * 4);
        bPre[q] = *(const float4*)(Wp + q * 4);
    }

    f32x4 acc[4][4];
#pragma unroll
    for (int i = 0; i < 4; ++i)
#pragma unroll
        for (int j = 0; j < 4; ++j) acc[i][j] = (f32x4){0.f, 0.f, 0.f, 0.f};

    const int wv = tid >> 6;
    const int wm = (wv >> 1) * 64;
    const int wn = (wv & 1) * 64;
    const int ln = tid & 63;
    const int fr = ln & 15;
    const int fq = ln >> 4;

    float rowsum = 0.0f;

    for (int ks = 0; ks < KSTEPS; ++ks) {
        if (DO_LEN) {
#pragma unroll
            for (int q = 0; q < 4; ++q)
                rowsum += aPre[q].x + aPre[q].y + aPre[q].z + aPre[q].w;
        }
        {
            uint32* ad = (uint32*)&At[row * PAD + kh * 16];
            uint32* bd = (uint32*)&Bt[row * PAD + kh * 16];
            uint4 au, bu;
            au.x = pk_bf16(aPre[0].x, aPre[0].y); au.y = pk_bf16(aPre[0].z, aPre[0].w);
            au.z = pk_bf16(aPre[1].x, aPre[1].y); au.w = pk_bf16(aPre[1].z, aPre[1].w);
            *(uint4*)ad = au;
            au.x = pk_bf16(aPre[2].x, aPre[2].y); au.y = pk_bf16(aPre[2].z, aPre[2].w);
            au.z = pk_bf16(aPre[3].x, aPre[3].y); au.w = pk_bf16(aPre[3].z, aPre[3].w);
            *(uint4*)(ad + 4) = au;
            bu.x = pk_bf16(bPre[0].x, bPre[0].y); bu.y = pk_bf16(bPre[0].z, bPre[0].w);
            bu.z = pk_bf16(bPre[1].x, bPre[1].y); bu.w = pk_bf16(bPre[1].z, bPre[1].w);
            *(uint4*)bd = bu;
            bu.x = pk_bf16(bPre[2].x, bPre[2].y); bu.y = pk_bf16(bPre[2].z, bPre[2].w);
            bu.z = pk_bf16(bPre[3].x, bPre[3].y); bu.w = pk_bf16(bPre[3].z, bPre[3].w);
            *(uint4*)(bd + 4) = bu;
        }
        __syncthreads();
        if (ks + 1 < KSTEPS) {
#pragma unroll
            for (int q = 0; q < 4; ++q) {
                aPre[q] = *(const float4*)(Ap + (ks + 1) * 32 + q * 4);
                bPre[q] = *(const float4*)(Wp + (ks + 1) * 32 + q * 4);
            }
        }
        bf16x8 aF[4], bF[4];
#pragma unroll
        for (int i = 0; i < 4; ++i) {
            aF[i] = *(const bf16x8*)&At[(wm + i * 16 + fr) * PAD + fq * 8];
            bF[i] = *(const bf16x8*)&Bt[(wn + i * 16 + fr) * PAD + fq * 8];
        }
#pragma unroll
        for (int i = 0; i < 4; ++i)
#pragma unroll
            for (int j = 0; j < 4; ++j)
                acc[i][j] = __builtin_amdgcn_mfma_f32_16x16x32_bf16(
                                aF[i], bF[j], acc[i][j], 0, 0, 0);
        __syncthreads();
    }

#pragma unroll
    for (int i = 0; i < 4; ++i) {
#pragma unroll
        for (int j = 0; j < 4; ++j) {
            const int n = n0 + wn + j * 16 + fr;
            const float bn = bias[n];
            const int mbase = m0 + wm + i * 16 + fq * 4;
#pragma unroll
            for (int r = 0; r < 4; ++r)
                C[(size_t)(mbase + r) * NDIM + n] = acc[i][j][r] + bn;
        }
    }

    if (DO_LEN && blockIdx.y == 0) {
        rowsum += __shfl_xor(rowsum, 1);
        if (kh == 0 && rowsum != 0.0f)
            atomicAdd(&lengths[(m0 + row) >> 11], 1);
    }
}

// ---------------------------------------------------------------------------
// Barrier-minimal MFMA GRU scan (R16-proven) + optional fused gx1 TAIL.
// Recurrence: wave w owns j in [w*16,w*16+16), 12 chained mfma f16 per step,
// one barrier. TAIL (WRITE_SEQ only): after the recurrence, this block computes
// gx1 = out0[b] @ Wih1^T + bih1 for ITS batch (A-operand L2-hot; removes the
// separate gx1 dispatch). 8 waves = 2 groups x 4 waves; group g owns m-tiles
// [g*8, g*8+8); Wih1 n-block staged once per nb.
// ---------------------------------------------------------------------------
#define SCAN_STEP(PR, CXR, CXZ, CXN)                                              \
    {                                                                             \
        const _Float16* hb = (const _Float16*)&hbuf[PR][0];                       \
        f16x8 ha0 = *(const f16x8*)(hb + 0 * 32 + fq * 8);                        \
        f16x8 ha1 = *(const f16x8*)(hb + 1 * 32 + fq * 8);                        \
        f16x8 ha2 = *(const f16x8*)(hb + 2 * 32 + fq * 8);                        \
        f16x8 ha3 = *(const f16x8*)(hb + 3 * 32 + fq * 8);                        \
        f32x4 accr = (f32x4){0.f,0.f,0.f,0.f};                                    \
        f32x4 accz = (f32x4){0.f,0.f,0.f,0.f};                                    \
        f32x4 accn = (f32x4){0.f,0.f,0.f,0.f};                                    \
        accr = __builtin_amdgcn_mfma_f32_16x16x32_f16(ha0, wR0, accr, 0, 0, 0);   \
        accz = __builtin_amdgcn_mfma_f32_16x16x32_f16(ha0, wZ0, accz, 0, 0, 0);   \
        accn = __builtin_amdgcn_mfma_f32_16x16x32_f16(ha0, wN0, accn, 0, 0, 0);   \
        accr = __builtin_amdgcn_mfma_f32_16x16x32_f16(ha1, wR1, accr, 0, 0, 0);   \
        accz = __builtin_amdgcn_mfma_f32_16x16x32_f16(ha1, wZ1, accz, 0, 0, 0);   \
        accn = __builtin_amdgcn_mfma_f32_16x16x32_f16(ha1, wN1, accn, 0, 0, 0);   \
        accr = __builtin_amdgcn_mfma_f32_16x16x32_f16(ha2, wR2, accr, 0, 0, 0);   \
        accz = __builtin_amdgcn_mfma_f32_16x16x32_f16(ha2, wZ2, accz, 0, 0, 0);   \
        accn = __builtin_amdgcn_mfma_f32_16x16x32_f16(ha2, wN2, accn, 0, 0, 0);   \
        accr = __builtin_amdgcn_mfma_f32_16x16x32_f16(ha3, wR3, accr, 0, 0, 0);   \
        accz = __builtin_amdgcn_mfma_f32_16x16x32_f16(ha3, wZ3, accz, 0, 0, 0);   \
        accn = __builtin_amdgcn_mfma_f32_16x16x32_f16(ha3, wN3, accn, 0, 0, 0);   \
        float ar = accr[0], az = accz[0], an = accn[0];                           \
        int tp = t + 2; if (tp > T_DIM - 1) tp = T_DIM - 1;                       \
        const float* gp = gxb + (size_t)tp * G_DIM + jl;                          \
        float nxr = gp[0], nxz = gp[128], nxn = gp[256];                          \
        float r  = sigmoid_f(CXR + ar + bhr);                                     \
        float z  = sigmoid_f(CXZ + az + bhz);                                     \
        float nn = tanh_f(CXN + r * (an + bhn));                                  \
        float hnew = nn + z * (h_prev - nn);                                      \
        h_prev = hnew;                                                            \
        if (fq == 0) {                                                            \
            ((_Float16*)&hbuf[PR ^ 1][0])[jl] = (_Float16)hnew;                   \
            if (WRITE_SEQ) seqb[(size_t)t * H_DIM + jl] = hnew;                   \
        }                                                                         \
        CXR = nxr; CXZ = nxz; CXN = nxn;                                          \
        FAST_BARRIER()                                                            \
    }

template<bool WRITE_SEQ>
__global__ __attribute__((amdgpu_flat_work_group_size(512, 512),
                          amdgpu_waves_per_eu(2, 2)))
void gru_scan_mfma_kernel(const float* __restrict__ gx,    // [B,T,3H] (incl b_ih)
                          const float* __restrict__ whh,   // [3H,H] this layer
                          const float* __restrict__ bhh,   // [3H]
                          const int*   __restrict__ lengths,
                          float* __restrict__ seq_out,     // [B,T,H] if WRITE_SEQ
                          float* __restrict__ final_out,   // [B,H]  if !WRITE_SEQ
                          const float* __restrict__ wih1,  // tail W (WRITE_SEQ)
                          const float* __restrict__ bih1,  // tail bias
                          float* __restrict__ gx1out)      // tail out = gx buffer
{
    __shared__ __align__(16) uint32 hbuf[2][68];
    __shared__ __align__(16) unsigned short Wt[4 * 128 * 40];     // tail B
    __shared__ __align__(16) unsigned short At2[2][4 * 128 * 40]; // tail A per group

    const int b   = blockIdx.x;
    const int tid = threadIdx.x;
    const int w   = tid >> 6;
    const int ln  = tid & 63;
    const int fr  = ln & 15;
    const int fq  = ln >> 4;
    const int jl  = w * 16 + fr;

    f16x8 wR0, wR1, wR2, wR3, wZ0, wZ1, wZ2, wZ3, wN0, wN1, wN2, wN3;
    {
        const float* base = whh + (size_t)jl * H_DIM + fq * 8;
#define LOADW(dst, g, c)                                                          \
        {                                                                         \
            const float* wp = base + (size_t)(g) * 128 * H_DIM + (c) * 32;        \
            float4 v0 = *(const float4*)wp;                                       \
            float4 v1 = *(const float4*)(wp + 4);                                 \
            u32x4 u;                                                              \
            u.x = packf16(v0.x, v0.y); u.y = packf16(v0.z, v0.w);                 \
            u.z = packf16(v1.x, v1.y); u.w = packf16(v1.z, v1.w);                 \
            dst = __builtin_bit_cast(f16x8, u);                                   \
        }
        LOADW(wR0, 0, 0) LOADW(wR1, 0, 1) LOADW(wR2, 0, 2) LOADW(wR3, 0, 3)
        LOADW(wZ0, 1, 0) LOADW(wZ1, 1, 1) LOADW(wZ2, 1, 2) LOADW(wZ3, 1, 3)
        LOADW(wN0, 2, 0) LOADW(wN1, 2, 1) LOADW(wN2, 2, 2) LOADW(wN3, 2, 3)
#undef LOADW
    }

    const int len = lengths[b];
    const float* gxb = gx + (size_t)b * T_DIM * G_DIM;
    float* seqb = WRITE_SEQ ? (seq_out + (size_t)b * T_DIM * H_DIM) : nullptr;

    const float bhr = bhh[jl], bhz = bhh[jl + 128], bhn = bhh[jl + 256];

    float exr = gxb[jl],         exz = gxb[jl + 128],         exn = gxb[jl + 256];
    float oxr = gxb[G_DIM + jl], oxz = gxb[G_DIM + jl + 128], oxn = gxb[G_DIM + jl + 256];

    for (int i = tid; i < 2 * 68; i += 512) ((uint32*)hbuf)[i] = 0u;
    __syncthreads();

    float h_prev = 0.0f;

    int t = 0;
    while (t < len) {
        SCAN_STEP(0, exr, exz, exn)
        ++t;
        if (t >= len) break;
        SCAN_STEP(1, oxr, oxz, oxn)
        ++t;
    }

    if (!WRITE_SEQ) {
        if (fq == 0)
            final_out[(size_t)b * H_DIM + jl] = h_prev;
        return;
    }

    // ---------------- fused gx1 tail (scan-0 only) ----------------
    // gx1[b] = out0[b] @ wih1^T + bih1. 2 groups x 4 waves; group g owns
    // m-tiles [g*8, g*8+8). Uniform barriers across all 512 threads.
    {
        __syncthreads();                       // recurrence LDS quiesced
        const int g    = w >> 2;               // group 0/1
        const int wl   = w & 3;                // wave in group
        const int wm   = (wl >> 1) * 64;
        const int wn   = (wl & 1) * 64;
        const int r    = (tid & 255) >> 1;     // staging row within group
        const int h    = tid & 1;              // k-half
        const int rw   = tid >> 2;             // W staging row (512-thread)
        const int kq4  = tid & 3;              // W staging k-chunk
        float* gx1b = gx1out + (size_t)b * T_DIM * G_DIM;

        for (int nb = 0; nb < 3; ++nb) {
            {   // stage Wih1 rows [nb*128,+128): thread (rw,kq4) -> 32 floats
                const float* wp = wih1 + (size_t)(nb * 128 + rw) * H_DIM + kq4 * 32;
#pragma unroll
                for (int p = 0; p < 4; ++p) {
                    float4 w0 = *(const float4*)(wp + p * 8);
                    float4 w1 = *(const float4*)(wp + p * 8 + 4);
                    uint4 u;
                    u.x = pk_bf16(w0.x, w0.y); u.y = pk_bf16(w0.z, w0.w);
                    u.z = pk_bf16(w1.x, w1.y); u.w = pk_bf16(w1.z, w1.w);
                    *(uint4*)&Wt[kq4 * 5120 + rw * 40 + p * 8] = u;
                }
            }
            __syncthreads();

            for (int mtl = 0; mtl < 8; ++mtl) {
                const int mt = g * 8 + mtl;
                {   // stage A tile (out0 rows [mt*128,+128)) into group's At2
                    const float* ap = seqb + (size_t)(mt * 128 + r) * H_DIM + h * 64;
#pragma unroll
                    for (int p = 0; p < 8; ++p) {
                        const int kl = h * 64 + p * 8;
                        const int ks = kl >> 5;
                        const int fs = (kl & 31) >> 3;
                        float4 a0 = *(const float4*)(ap + p * 8);
                        float4 a1 = *(const float4*)(ap + p * 8 + 4);
                        uint4 u;
                        u.x = pk_bf16(a0.x, a0.y); u.y = pk_bf16(a0.z, a0.w);
                        u.z = pk_bf16(a1.x, a1.y); u.w = pk_bf16(a1.z, a1.w);
                        *(uint4*)&At2[g][ks * 5120 + r * 40 + fs * 8] = u;
                    }
                }
                __syncthreads();

                f32x4 acc[4][4];
#pragma unroll
                for (int i = 0; i < 4; ++i)
#pragma unroll
                    for (int j = 0; j < 4; ++j) acc[i][j] = (f32x4){0.f,0.f,0.f,0.f};

#pragma unroll
                for (int ks = 0; ks < 4; ++ks) {
                    bf16x8 aF[4], bF[4];
#pragma unroll
                    for (int i = 0; i < 4; ++i) {
                        aF[i] = *(const bf16x8*)&At2[g][ks * 5120 + (wm + i * 16 + fr) * 40 + fq * 8];
                        bF[i] = *(const bf16x8*)&Wt[ks * 5120 + (wn + i * 16 + fr) * 40 + fq * 8];
                    }
#pragma unroll
                    for (int i = 0; i < 4; ++i)
#pragma unroll
                        for (int j = 0; j < 4; ++j)
                            acc[i][j] = __builtin_amdgcn_mfma_f32_16x16x32_bf16(
                                            aF[i], bF[j], acc[i][j], 0, 0, 0);
                }
                __syncthreads();   // group done reading At2 (and Wt reads this mtl)

#pragma unroll
                for (int i = 0; i < 4; ++i) {
#pragma unroll
                    for (int j = 0; j < 4; ++j) {
                        const int n = nb * 128 + wn + j * 16 + fr;
                        const float bn = bih1[n];
                        const int mb = mt * 128 + wm + i * 16 + fq * 4;
#pragma unroll
                        for (int rr = 0; rr < 4; ++rr)
                            gx1b[(size_t)(mb + rr) * G_DIM + n] = acc[i][j][rr] + bn;
                    }
                }
            }
        }
    }
}

extern "C" void kernel_launch(void* const* d_in, const int* in_sizes, int n_in,
                              void* d_out, int out_size, void* d_ws, size_t ws_size,
                              hipStream_t stream)
{
    (void)in_sizes; (void)n_in; (void)out_size; (void)ws_size;
    const float* x      = (const float*)d_in[0];
    const float* w_proj = (const float*)d_in[1];
    const float* b_proj = (const float*)d_in[2];
    const float* w_ih   = (const float*)d_in[3];
    const float* w_hh   = (const float*)d_in[4];
    const float* b_ih   = (const float*)d_in[5];
    const float* b_hh   = (const float*)d_in[6];
    float* out = (float*)d_out;

    char*  ws      = (char*)d_ws;
    float* feat    = (float*)(ws);                    // out0 buffer
    float* gxbuf   = (float*)(ws + 67108864ull);
    int*   lengths = (int*)  (ws + 268435456ull);

    hipMemsetAsync(lengths, 0, B_DIM * sizeof(int), stream);

    const int M = B_DIM * T_DIM;
    // 1) feat = x @ w_proj^T + b_proj (+ lengths)   M=131072, N=128, K=512
    gemm_mfma_kernel<F_DIM, H_DIM, true>
        <<<dim3(M / 128, 1), 256, 0, stream>>>(x, w_proj, b_proj, feat, lengths);
    // 2) gx0 = feat @ w_ih[0]^T + b_ih[0]           M=131072, N=384, K=128
    gemm_mfma_kernel<H_DIM, G_DIM, false>
        <<<dim3(M / 128, 3), 256, 0, stream>>>(feat, w_ih, b_ih, gxbuf, nullptr);
    // 3) layer-0 scan -> out0, then fused gx1 tail (overwrites gxbuf per batch)
    gru_scan_mfma_kernel<true><<<B_DIM, 512, 0, stream>>>(
        gxbuf, w_hh, b_hh, lengths, feat, nullptr,
        w_ih + G_DIM * H_DIM, b_ih + G_DIM, gxbuf);
    // 4) layer-1 scan -> final top-layer state
    gru_scan_mfma_kernel<false><<<B_DIM, 512, 0, stream>>>(
        gxbuf, w_hh + G_DIM * H_DIM, b_hh + G_DIM, lengths, nullptr, out,
        nullptr, nullptr, nullptr);
}

// Round 22
// 2754.637 us; speedup vs baseline: 1.0473x; 1.0473x over previous
//
#include <hip/hip_runtime.h>

#define B_DIM 64
#define T_DIM 2048
#define F_DIM 512
#define H_DIM 128
#define G_DIM 384  // 3*H

typedef _Float16 half2_t __attribute__((ext_vector_type(2)));
typedef _Float16 f16x8   __attribute__((ext_vector_type(8)));
typedef unsigned int uint32;
typedef uint32 u32x4 __attribute__((ext_vector_type(4)));
typedef short bf16x8 __attribute__((ext_vector_type(8)));
typedef float f32x4  __attribute__((ext_vector_type(4)));

__device__ __forceinline__ float sigmoid_f(float x) {
    return __fdividef(1.0f, 1.0f + __expf(-x));
}
__device__ __forceinline__ float tanh_f(float x) {
    return __fdividef(2.0f, 1.0f + __expf(-2.0f * x)) - 1.0f;
}

__device__ __forceinline__ uint32 packf16(float a, float b) {
    half2_t p; p.x = (_Float16)a; p.y = (_Float16)b;
    return __builtin_bit_cast(uint32, p);
}

__device__ __forceinline__ uint32 pk_bf16(float lo, float hi) {
    uint32 r;
    asm("v_cvt_pk_bf16_f32 %0, %1, %2" : "=v"(r) : "v"(lo), "v"(hi));
    return r;
}

#define FAST_BARRIER()                                                            \
    __builtin_amdgcn_sched_barrier(0);                                            \
    asm volatile("s_waitcnt lgkmcnt(0)" ::: "memory");                            \
    __builtin_amdgcn_s_barrier();                                                 \
    __builtin_amdgcn_sched_barrier(0);

// ---------------------------------------------------------------------------
// bf16 MFMA GEMM (R10-proven): C[M x NDIM] = A @ W^T + bias; optional lengths.
// OUT_T = float (feat) or _Float16 (gx buffers: halves write + scan-read BW).
// ---------------------------------------------------------------------------
template<int KDIM, int NDIM, bool DO_LEN, typename OUT_T>
__global__ __launch_bounds__(256)
void gemm_mfma_kernel(const float* __restrict__ A, const float* __restrict__ W,
                      const float* __restrict__ bias, OUT_T* __restrict__ C,
                      int* __restrict__ lengths)
{
    constexpr int KSTEPS = KDIM / 32;
    constexpr int PAD = 40;
    __shared__ __align__(16) unsigned short At[128 * PAD];
    __shared__ __align__(16) unsigned short Bt[128 * PAD];

    const int tid = threadIdx.x;
    const int m0  = blockIdx.x * 128;
    const int n0  = blockIdx.y * 128;
    const int row = tid >> 1;
    const int kh  = tid & 1;

    const float* Ap = A + (size_t)(m0 + row) * KDIM + kh * 16;
    const float* Wp = W + (size_t)(n0 + row) * KDIM + kh * 16;

    float4 aPre[4], bPre[4];
#pragma unroll
    for (int q = 0; q < 4; ++q) {
        aPre[q] = *(const float4*)(Ap + q * 4);
        bPre[q] = *(const float4*)(Wp + q * 4);
    }

    f32x4 acc[4][4];
#pragma unroll
    for (int i = 0; i < 4; ++i)
#pragma unroll
        for (int j = 0; j < 4; ++j) acc[i][j] = (f32x4){0.f, 0.f, 0.f, 0.f};

    const int wv = tid >> 6;
    const int wm = (wv >> 1) * 64;
    const int wn = (wv & 1) * 64;
    const int ln = tid & 63;
    const int fr = ln & 15;
    const int fq = ln >> 4;

    float rowsum = 0.0f;

    for (int ks = 0; ks < KSTEPS; ++ks) {
        if (DO_LEN) {
#pragma unroll
            for (int q = 0; q < 4; ++q)
                rowsum += aPre[q].x + aPre[q].y + aPre[q].z + aPre[q].w;
        }
        {
            uint32* ad = (uint32*)&At[row * PAD + kh * 16];
            uint32* bd = (uint32*)&Bt[row * PAD + kh * 16];
            uint4 au, bu;
            au.x = pk_bf16(aPre[0].x, aPre[0].y); au.y = pk_bf16(aPre[0].z, aPre[0].w);
            au.z = pk_bf16(aPre[1].x, aPre[1].y); au.w = pk_bf16(aPre[1].z, aPre[1].w);
            *(uint4*)ad = au;
            au.x = pk_bf16(aPre[2].x, aPre[2].y); au.y = pk_bf16(aPre[2].z, aPre[2].w);
            au.z = pk_bf16(aPre[3].x, aPre[3].y); au.w = pk_bf16(aPre[3].z, aPre[3].w);
            *(uint4*)(ad + 4) = au;
            bu.x = pk_bf16(bPre[0].x, bPre[0].y); bu.y = pk_bf16(bPre[0].z, bPre[0].w);
            bu.z = pk_bf16(bPre[1].x, bPre[1].y); bu.w = pk_bf16(bPre[1].z, bPre[1].w);
            *(uint4*)bd = bu;
            bu.x = pk_bf16(bPre[2].x, bPre[2].y); bu.y = pk_bf16(bPre[2].z, bPre[2].w);
            bu.z = pk_bf16(bPre[3].x, bPre[3].y); bu.w = pk_bf16(bPre[3].z, bPre[3].w);
            *(uint4*)(bd + 4) = bu;
        }
        __syncthreads();
        if (ks + 1 < KSTEPS) {
#pragma unroll
            for (int q = 0; q < 4; ++q) {
                aPre[q] = *(const float4*)(Ap + (ks + 1) * 32 + q * 4);
                bPre[q] = *(const float4*)(Wp + (ks + 1) * 32 + q * 4);
            }
        }
        bf16x8 aF[4], bF[4];
#pragma unroll
        for (int i = 0; i < 4; ++i) {
            aF[i] = *(const bf16x8*)&At[(wm + i * 16 + fr) * PAD + fq * 8];
            bF[i] = *(const bf16x8*)&Bt[(wn + i * 16 + fr) * PAD + fq * 8];
        }
#pragma unroll
        for (int i = 0; i < 4; ++i)
#pragma unroll
            for (int j = 0; j < 4; ++j)
                acc[i][j] = __builtin_amdgcn_mfma_f32_16x16x32_bf16(
                                aF[i], bF[j], acc[i][j], 0, 0, 0);
        __syncthreads();
    }

#pragma unroll
    for (int i = 0; i < 4; ++i) {
#pragma unroll
        for (int j = 0; j < 4; ++j) {
            const int n = n0 + wn + j * 16 + fr;
            const float bn = bias[n];
            const int mbase = m0 + wm + i * 16 + fq * 4;
#pragma unroll
            for (int r = 0; r < 4; ++r)
                C[(size_t)(mbase + r) * NDIM + n] = (OUT_T)(acc[i][j][r] + bn);
        }
    }

    if (DO_LEN && blockIdx.y == 0) {
        rowsum += __shfl_xor(rowsum, 1);
        if (kh == 0 && rowsum != 0.0f)
            atomicAdd(&lengths[(m0 + row) >> 11], 1);
    }
}

// ---------------------------------------------------------------------------
// Barrier-minimal MFMA GRU scan (R16-proven). One block per batch element,
// 512 threads = 8 waves. Wave w owns j in [w*16, w*16+16): 12 chained
// mfma_f32_16x16x32_f16 (A = h broadcast) give every lane the complete K=128
// dot for its (j, gate) in acc[0]. Redundant gate math across fq replicas;
// fq==0 writes h' f16. ONE barrier per step. 48 resident u32 weights.
// gx is consumed as f16 (R22: halves the scan's gx fetch stream).
// ---------------------------------------------------------------------------
#define SCAN_STEP(PR, CXR, CXZ, CXN)                                              \
    {                                                                             \
        const _Float16* hb = (const _Float16*)&hbuf[PR][0];                       \
        f16x8 ha0 = *(const f16x8*)(hb + 0 * 32 + fq * 8);                        \
        f16x8 ha1 = *(const f16x8*)(hb + 1 * 32 + fq * 8);                        \
        f16x8 ha2 = *(const f16x8*)(hb + 2 * 32 + fq * 8);                        \
        f16x8 ha3 = *(const f16x8*)(hb + 3 * 32 + fq * 8);                        \
        f32x4 accr = (f32x4){0.f,0.f,0.f,0.f};                                    \
        f32x4 accz = (f32x4){0.f,0.f,0.f,0.f};                                    \
        f32x4 accn = (f32x4){0.f,0.f,0.f,0.f};                                    \
        accr = __builtin_amdgcn_mfma_f32_16x16x32_f16(ha0, wR0, accr, 0, 0, 0);   \
        accz = __builtin_amdgcn_mfma_f32_16x16x32_f16(ha0, wZ0, accz, 0, 0, 0);   \
        accn = __builtin_amdgcn_mfma_f32_16x16x32_f16(ha0, wN0, accn, 0, 0, 0);   \
        accr = __builtin_amdgcn_mfma_f32_16x16x32_f16(ha1, wR1, accr, 0, 0, 0);   \
        accz = __builtin_amdgcn_mfma_f32_16x16x32_f16(ha1, wZ1, accz, 0, 0, 0);   \
        accn = __builtin_amdgcn_mfma_f32_16x16x32_f16(ha1, wN1, accn, 0, 0, 0);   \
        accr = __builtin_amdgcn_mfma_f32_16x16x32_f16(ha2, wR2, accr, 0, 0, 0);   \
        accz = __builtin_amdgcn_mfma_f32_16x16x32_f16(ha2, wZ2, accz, 0, 0, 0);   \
        accn = __builtin_amdgcn_mfma_f32_16x16x32_f16(ha2, wN2, accn, 0, 0, 0);   \
        accr = __builtin_amdgcn_mfma_f32_16x16x32_f16(ha3, wR3, accr, 0, 0, 0);   \
        accz = __builtin_amdgcn_mfma_f32_16x16x32_f16(ha3, wZ3, accz, 0, 0, 0);   \
        accn = __builtin_amdgcn_mfma_f32_16x16x32_f16(ha3, wN3, accn, 0, 0, 0);   \
        float ar = accr[0], az = accz[0], an = accn[0];                           \
        int tp = t + 2; if (tp > T_DIM - 1) tp = T_DIM - 1;                       \
        const _Float16* gp = gxb + (size_t)tp * G_DIM + jl;                       \
        float nxr = (float)gp[0], nxz = (float)gp[128], nxn = (float)gp[256];     \
        float r  = sigmoid_f(CXR + ar + bhr);                                     \
        float z  = sigmoid_f(CXZ + az + bhz);                                     \
        float nn = tanh_f(CXN + r * (an + bhn));                                  \
        float hnew = nn + z * (h_prev - nn);                                      \
        h_prev = hnew;                                                            \
        if (fq == 0) {                                                            \
            ((_Float16*)&hbuf[PR ^ 1][0])[jl] = (_Float16)hnew;                   \
            if (WRITE_SEQ) seqb[(size_t)t * H_DIM + jl] = hnew;                   \
        }                                                                         \
        CXR = nxr; CXZ = nxz; CXN = nxn;                                          \
        FAST_BARRIER()                                                            \
    }

template<bool WRITE_SEQ>
__global__ __attribute__((amdgpu_flat_work_group_size(512, 512),
                          amdgpu_waves_per_eu(2, 2)))
void gru_scan_mfma_kernel(const _Float16* __restrict__ gx,  // [B,T,3H] f16 (incl b_ih)
                          const float* __restrict__ whh,    // [3H,H] this layer
                          const float* __restrict__ bhh,    // [3H]
                          const int*   __restrict__ lengths,
                          float* __restrict__ seq_out,      // [B,T,H] if WRITE_SEQ
                          float* __restrict__ final_out)    // [B,H]  if !WRITE_SEQ
{
    __shared__ __align__(16) uint32 hbuf[2][68];

    const int b   = blockIdx.x;
    const int tid = threadIdx.x;
    const int w   = tid >> 6;
    const int ln  = tid & 63;
    const int fr  = ln & 15;
    const int fq  = ln >> 4;
    const int jl  = w * 16 + fr;

    f16x8 wR0, wR1, wR2, wR3, wZ0, wZ1, wZ2, wZ3, wN0, wN1, wN2, wN3;
    {
        const float* base = whh + (size_t)jl * H_DIM + fq * 8;
#define LOADW(dst, g, c)                                                          \
        {                                                                         \
            const float* wp = base + (size_t)(g) * 128 * H_DIM + (c) * 32;        \
            float4 v0 = *(const float4*)wp;                                       \
            float4 v1 = *(const float4*)(wp + 4);                                 \
            u32x4 u;                                                              \
            u.x = packf16(v0.x, v0.y); u.y = packf16(v0.z, v0.w);                 \
            u.z = packf16(v1.x, v1.y); u.w = packf16(v1.z, v1.w);                 \
            dst = __builtin_bit_cast(f16x8, u);                                   \
        }
        LOADW(wR0, 0, 0) LOADW(wR1, 0, 1) LOADW(wR2, 0, 2) LOADW(wR3, 0, 3)
        LOADW(wZ0, 1, 0) LOADW(wZ1, 1, 1) LOADW(wZ2, 1, 2) LOADW(wZ3, 1, 3)
        LOADW(wN0, 2, 0) LOADW(wN1, 2, 1) LOADW(wN2, 2, 2) LOADW(wN3, 2, 3)
#undef LOADW
    }

    const int len = lengths[b];
    const _Float16* gxb = gx + (size_t)b * T_DIM * G_DIM;
    float* seqb = WRITE_SEQ ? (seq_out + (size_t)b * T_DIM * H_DIM) : nullptr;

    const float bhr = bhh[jl], bhz = bhh[jl + 128], bhn = bhh[jl + 256];

    // gx ping-pong prefetch (2 steps ahead); fq replicas load redundantly
    float exr = (float)gxb[jl],         exz = (float)gxb[jl + 128];
    float exn = (float)gxb[jl + 256];
    float oxr = (float)gxb[G_DIM + jl], oxz = (float)gxb[G_DIM + jl + 128];
    float oxn = (float)gxb[G_DIM + jl + 256];

    for (int i = tid; i < 2 * 68; i += 512) ((uint32*)hbuf)[i] = 0u;
    __syncthreads();

    float h_prev = 0.0f;

    int t = 0;
    while (t < len) {
        SCAN_STEP(0, exr, exz, exn)
        ++t;
        if (t >= len) break;
        SCAN_STEP(1, oxr, oxz, oxn)
        ++t;
    }

    if (!WRITE_SEQ && fq == 0)
        final_out[(size_t)b * H_DIM + jl] = h_prev;
}

extern "C" void kernel_launch(void* const* d_in, const int* in_sizes, int n_in,
                              void* d_out, int out_size, void* d_ws, size_t ws_size,
                              hipStream_t stream)
{
    (void)in_sizes; (void)n_in; (void)out_size; (void)ws_size;
    const float* x      = (const float*)d_in[0];
    const float* w_proj = (const float*)d_in[1];
    const float* b_proj = (const float*)d_in[2];
    const float* w_ih   = (const float*)d_in[3];
    const float* w_hh   = (const float*)d_in[4];
    const float* b_ih   = (const float*)d_in[5];
    const float* b_hh   = (const float*)d_in[6];
    float* out = (float*)d_out;

    // ws: [0,64MB) feat/out0 (f32); [64MB,+96MB) gx (f16); [256MB,+256B) lengths
    char*     ws      = (char*)d_ws;
    float*    feat    = (float*)(ws);
    _Float16* gxbuf   = (_Float16*)(ws + 67108864ull);
    int*      lengths = (int*)  (ws + 268435456ull);

    hipMemsetAsync(lengths, 0, B_DIM * sizeof(int), stream);

    const int M = B_DIM * T_DIM;
    // 1) feat = x @ w_proj^T + b_proj (+ lengths)   M=131072, N=128, K=512
    gemm_mfma_kernel<F_DIM, H_DIM, true, float>
        <<<dim3(M / 128, 1), 256, 0, stream>>>(x, w_proj, b_proj, feat, lengths);
    // 2) gx0 = feat @ w_ih[0]^T + b_ih[0]  (f16 out) M=131072, N=384, K=128
    gemm_mfma_kernel<H_DIM, G_DIM, false, _Float16>
        <<<dim3(M / 128, 3), 256, 0, stream>>>(feat, w_ih, b_ih, gxbuf, nullptr);
    // 3) layer-0 scan -> out0 (feat buffer)
    gru_scan_mfma_kernel<true><<<B_DIM, 512, 0, stream>>>(
        gxbuf, w_hh, b_hh, lengths, feat, nullptr);
    // 4) gx1 = out0 @ w_ih[1]^T + b_ih[1]  (f16 out)
    gemm_mfma_kernel<H_DIM, G_DIM, false, _Float16>
        <<<dim3(M / 128, 3), 256, 0, stream>>>(feat, w_ih + G_DIM * H_DIM, b_ih + G_DIM, gxbuf, nullptr);
    // 5) layer-1 scan -> final top-layer state
    gru_scan_mfma_kernel<false><<<B_DIM, 512, 0, stream>>>(
        gxbuf, w_hh + G_DIM * H_DIM, b_hh + G_DIM, lengths, nullptr, out);
}

// Round 23
// 2008.452 us; speedup vs baseline: 1.4364x; 1.3715x over previous
//
#include <hip/hip_runtime.h>

#define B_DIM 64
#define T_DIM 2048
#define F_DIM 512
#define H_DIM 128
#define G_DIM 384  // 3*H

typedef _Float16 half2_t __attribute__((ext_vector_type(2)));
typedef _Float16 f16x8   __attribute__((ext_vector_type(8)));
typedef unsigned int uint32;
typedef uint32 u32x4 __attribute__((ext_vector_type(4)));
typedef short bf16x8 __attribute__((ext_vector_type(8)));
typedef float f32x4  __attribute__((ext_vector_type(4)));

__device__ __forceinline__ float sigmoid_f(float x) {
    return __fdividef(1.0f, 1.0f + __expf(-x));
}
__device__ __forceinline__ float tanh_f(float x) {
    return __fdividef(2.0f, 1.0f + __expf(-2.0f * x)) - 1.0f;
}

__device__ __forceinline__ uint32 packf16(float a, float b) {
    half2_t p; p.x = (_Float16)a; p.y = (_Float16)b;
    return __builtin_bit_cast(uint32, p);
}

__device__ __forceinline__ uint32 pk_bf16(float lo, float hi) {
    uint32 r;
    asm("v_cvt_pk_bf16_f32 %0, %1, %2" : "=v"(r) : "v"(lo), "v"(hi));
    return r;
}

#define FAST_BARRIER()                                                            \
    __builtin_amdgcn_sched_barrier(0);                                            \
    asm volatile("s_waitcnt lgkmcnt(0)" ::: "memory");                            \
    __builtin_amdgcn_s_barrier();                                                 \
    __builtin_amdgcn_sched_barrier(0);

// ---------------------------------------------------------------------------
// bf16 MFMA GEMM (R10-proven): C[M x NDIM] = A @ W^T + bias; optional lengths.
// OUT_T = float (feat) or _Float16 (gx buffers: halves write + scan-read BW).
// R23: lengths via per-wave ballot+popcount -> ONE atomic per wave (4096 total)
// instead of ~98K same-address atomics (L2 same-line serialization, G12).
// ---------------------------------------------------------------------------
template<int KDIM, int NDIM, bool DO_LEN, typename OUT_T>
__global__ __launch_bounds__(256)
void gemm_mfma_kernel(const float* __restrict__ A, const float* __restrict__ W,
                      const float* __restrict__ bias, OUT_T* __restrict__ C,
                      int* __restrict__ lengths)
{
    constexpr int KSTEPS = KDIM / 32;
    constexpr int PAD = 40;
    __shared__ __align__(16) unsigned short At[128 * PAD];
    __shared__ __align__(16) unsigned short Bt[128 * PAD];

    const int tid = threadIdx.x;
    const int m0  = blockIdx.x * 128;
    const int n0  = blockIdx.y * 128;
    const int row = tid >> 1;
    const int kh  = tid & 1;

    const float* Ap = A + (size_t)(m0 + row) * KDIM + kh * 16;
    const float* Wp = W + (size_t)(n0 + row) * KDIM + kh * 16;

    float4 aPre[4], bPre[4];
#pragma unroll
    for (int q = 0; q < 4; ++q) {
        aPre[q] = *(const float4*)(Ap + q * 4);
        bPre[q] = *(const float4*)(Wp + q * 4);
    }

    f32x4 acc[4][4];
#pragma unroll
    for (int i = 0; i < 4; ++i)
#pragma unroll
        for (int j = 0; j < 4; ++j) acc[i][j] = (f32x4){0.f, 0.f, 0.f, 0.f};

    const int wv = tid >> 6;
    const int wm = (wv >> 1) * 64;
    const int wn = (wv & 1) * 64;
    const int ln = tid & 63;
    const int fr = ln & 15;
    const int fq = ln >> 4;

    float rowsum = 0.0f;

    for (int ks = 0; ks < KSTEPS; ++ks) {
        if (DO_LEN) {
#pragma unroll
            for (int q = 0; q < 4; ++q)
                rowsum += aPre[q].x + aPre[q].y + aPre[q].z + aPre[q].w;
        }
        {
            uint32* ad = (uint32*)&At[row * PAD + kh * 16];
            uint32* bd = (uint32*)&Bt[row * PAD + kh * 16];
            uint4 au, bu;
            au.x = pk_bf16(aPre[0].x, aPre[0].y); au.y = pk_bf16(aPre[0].z, aPre[0].w);
            au.z = pk_bf16(aPre[1].x, aPre[1].y); au.w = pk_bf16(aPre[1].z, aPre[1].w);
            *(uint4*)ad = au;
            au.x = pk_bf16(aPre[2].x, aPre[2].y); au.y = pk_bf16(aPre[2].z, aPre[2].w);
            au.z = pk_bf16(aPre[3].x, aPre[3].y); au.w = pk_bf16(aPre[3].z, aPre[3].w);
            *(uint4*)(ad + 4) = au;
            bu.x = pk_bf16(bPre[0].x, bPre[0].y); bu.y = pk_bf16(bPre[0].z, bPre[0].w);
            bu.z = pk_bf16(bPre[1].x, bPre[1].y); bu.w = pk_bf16(bPre[1].z, bPre[1].w);
            *(uint4*)bd = bu;
            bu.x = pk_bf16(bPre[2].x, bPre[2].y); bu.y = pk_bf16(bPre[2].z, bPre[2].w);
            bu.z = pk_bf16(bPre[3].x, bPre[3].y); bu.w = pk_bf16(bPre[3].z, bPre[3].w);
            *(uint4*)(bd + 4) = bu;
        }
        __syncthreads();
        if (ks + 1 < KSTEPS) {
#pragma unroll
            for (int q = 0; q < 4; ++q) {
                aPre[q] = *(const float4*)(Ap + (ks + 1) * 32 + q * 4);
                bPre[q] = *(const float4*)(Wp + (ks + 1) * 32 + q * 4);
            }
        }
        bf16x8 aF[4], bF[4];
#pragma unroll
        for (int i = 0; i < 4; ++i) {
            aF[i] = *(const bf16x8*)&At[(wm + i * 16 + fr) * PAD + fq * 8];
            bF[i] = *(const bf16x8*)&Bt[(wn + i * 16 + fr) * PAD + fq * 8];
        }
#pragma unroll
        for (int i = 0; i < 4; ++i)
#pragma unroll
            for (int j = 0; j < 4; ++j)
                acc[i][j] = __builtin_amdgcn_mfma_f32_16x16x32_bf16(
                                aF[i], bF[j], acc[i][j], 0, 0, 0);
        __syncthreads();
    }

#pragma unroll
    for (int i = 0; i < 4; ++i) {
#pragma unroll
        for (int j = 0; j < 4; ++j) {
            const int n = n0 + wn + j * 16 + fr;
            const float bn = bias[n];
            const int mbase = m0 + wm + i * 16 + fq * 4;
#pragma unroll
            for (int r = 0; r < 4; ++r)
                C[(size_t)(mbase + r) * NDIM + n] = (OUT_T)(acc[i][j][r] + bn);
        }
    }

    if (DO_LEN && blockIdx.y == 0) {
        // combine the two k-halves of each row's sum (lanes kh=0/1 adjacent)
        rowsum += __shfl_xor(rowsum, 1);
        // one ballot+popcount per wave, ONE atomic per wave; all 128 rows of
        // this block belong to batch m0/T_DIM (128 divides T_DIM)
        unsigned long long m = __ballot(kh == 0 && rowsum != 0.0f);
        int cnt = __popcll(m);
        if (ln == 0 && cnt > 0)
            atomicAdd(&lengths[m0 >> 11], cnt);
    }
}

// ---------------------------------------------------------------------------
// Barrier-minimal MFMA GRU scan (R16-proven). One block per batch element,
// 512 threads = 8 waves. Wave w owns j in [w*16, w*16+16): 12 chained
// mfma_f32_16x16x32_f16 (A = h broadcast) give every lane the complete K=128
// dot for its (j, gate) in acc[0]. Redundant gate math across fq replicas;
// fq==0 writes h' f16. ONE barrier per step. 48 resident u32 weights.
// gx is consumed as f16 (R22-proven: halves the scan's gx fetch stream).
// ---------------------------------------------------------------------------
#define SCAN_STEP(PR, CXR, CXZ, CXN)                                              \
    {                                                                             \
        const _Float16* hb = (const _Float16*)&hbuf[PR][0];                       \
        f16x8 ha0 = *(const f16x8*)(hb + 0 * 32 + fq * 8);                        \
        f16x8 ha1 = *(const f16x8*)(hb + 1 * 32 + fq * 8);                        \
        f16x8 ha2 = *(const f16x8*)(hb + 2 * 32 + fq * 8);                        \
        f16x8 ha3 = *(const f16x8*)(hb + 3 * 32 + fq * 8);                        \
        f32x4 accr = (f32x4){0.f,0.f,0.f,0.f};                                    \
        f32x4 accz = (f32x4){0.f,0.f,0.f,0.f};                                    \
        f32x4 accn = (f32x4){0.f,0.f,0.f,0.f};                                    \
        accr = __builtin_amdgcn_mfma_f32_16x16x32_f16(ha0, wR0, accr, 0, 0, 0);   \
        accz = __builtin_amdgcn_mfma_f32_16x16x32_f16(ha0, wZ0, accz, 0, 0, 0);   \
        accn = __builtin_amdgcn_mfma_f32_16x16x32_f16(ha0, wN0, accn, 0, 0, 0);   \
        accr = __builtin_amdgcn_mfma_f32_16x16x32_f16(ha1, wR1, accr, 0, 0, 0);   \
        accz = __builtin_amdgcn_mfma_f32_16x16x32_f16(ha1, wZ1, accz, 0, 0, 0);   \
        accn = __builtin_amdgcn_mfma_f32_16x16x32_f16(ha1, wN1, accn, 0, 0, 0);   \
        accr = __builtin_amdgcn_mfma_f32_16x16x32_f16(ha2, wR2, accr, 0, 0, 0);   \
        accz = __builtin_amdgcn_mfma_f32_16x16x32_f16(ha2, wZ2, accz, 0, 0, 0);   \
        accn = __builtin_amdgcn_mfma_f32_16x16x32_f16(ha2, wN2, accn, 0, 0, 0);   \
        accr = __builtin_amdgcn_mfma_f32_16x16x32_f16(ha3, wR3, accr, 0, 0, 0);   \
        accz = __builtin_amdgcn_mfma_f32_16x16x32_f16(ha3, wZ3, accz, 0, 0, 0);   \
        accn = __builtin_amdgcn_mfma_f32_16x16x32_f16(ha3, wN3, accn, 0, 0, 0);   \
        float ar = accr[0], az = accz[0], an = accn[0];                           \
        int tp = t + 2; if (tp > T_DIM - 1) tp = T_DIM - 1;                       \
        const _Float16* gp = gxb + (size_t)tp * G_DIM + jl;                       \
        float nxr = (float)gp[0], nxz = (float)gp[128], nxn = (float)gp[256];     \
        float r  = sigmoid_f(CXR + ar + bhr);                                     \
        float z  = sigmoid_f(CXZ + az + bhz);                                     \
        float nn = tanh_f(CXN + r * (an + bhn));                                  \
        float hnew = nn + z * (h_prev - nn);                                      \
        h_prev = hnew;                                                            \
        if (fq == 0) {                                                            \
            ((_Float16*)&hbuf[PR ^ 1][0])[jl] = (_Float16)hnew;                   \
            if (WRITE_SEQ) seqb[(size_t)t * H_DIM + jl] = hnew;                   \
        }                                                                         \
        CXR = nxr; CXZ = nxz; CXN = nxn;                                          \
        FAST_BARRIER()                                                            \
    }

template<bool WRITE_SEQ>
__global__ __attribute__((amdgpu_flat_work_group_size(512, 512),
                          amdgpu_waves_per_eu(2, 2)))
void gru_scan_mfma_kernel(const _Float16* __restrict__ gx,  // [B,T,3H] f16 (incl b_ih)
                          const float* __restrict__ whh,    // [3H,H] this layer
                          const float* __restrict__ bhh,    // [3H]
                          const int*   __restrict__ lengths,
                          float* __restrict__ seq_out,      // [B,T,H] if WRITE_SEQ
                          float* __restrict__ final_out)    // [B,H]  if !WRITE_SEQ
{
    __shared__ __align__(16) uint32 hbuf[2][68];

    const int b   = blockIdx.x;
    const int tid = threadIdx.x;
    const int w   = tid >> 6;
    const int ln  = tid & 63;
    const int fr  = ln & 15;
    const int fq  = ln >> 4;
    const int jl  = w * 16 + fr;

    f16x8 wR0, wR1, wR2, wR3, wZ0, wZ1, wZ2, wZ3, wN0, wN1, wN2, wN3;
    {
        const float* base = whh + (size_t)jl * H_DIM + fq * 8;
#define LOADW(dst, g, c)                                                          \
        {                                                                         \
            const float* wp = base + (size_t)(g) * 128 * H_DIM + (c) * 32;        \
            float4 v0 = *(const float4*)wp;                                       \
            float4 v1 = *(const float4*)(wp + 4);                                 \
            u32x4 u;                                                              \
            u.x = packf16(v0.x, v0.y); u.y = packf16(v0.z, v0.w);                 \
            u.z = packf16(v1.x, v1.y); u.w = packf16(v1.z, v1.w);                 \
            dst = __builtin_bit_cast(f16x8, u);                                   \
        }
        LOADW(wR0, 0, 0) LOADW(wR1, 0, 1) LOADW(wR2, 0, 2) LOADW(wR3, 0, 3)
        LOADW(wZ0, 1, 0) LOADW(wZ1, 1, 1) LOADW(wZ2, 1, 2) LOADW(wZ3, 1, 3)
        LOADW(wN0, 2, 0) LOADW(wN1, 2, 1) LOADW(wN2, 2, 2) LOADW(wN3, 2, 3)
#undef LOADW
    }

    const int len = lengths[b];
    const _Float16* gxb = gx + (size_t)b * T_DIM * G_DIM;
    float* seqb = WRITE_SEQ ? (seq_out + (size_t)b * T_DIM * H_DIM) : nullptr;

    const float bhr = bhh[jl], bhz = bhh[jl + 128], bhn = bhh[jl + 256];

    // gx ping-pong prefetch (2 steps ahead); fq replicas load redundantly
    float exr = (float)gxb[jl],         exz = (float)gxb[jl + 128];
    float exn = (float)gxb[jl + 256];
    float oxr = (float)gxb[G_DIM + jl], oxz = (float)gxb[G_DIM + jl + 128];
    float oxn = (float)gxb[G_DIM + jl + 256];

    for (int i = tid; i < 2 * 68; i += 512) ((uint32*)hbuf)[i] = 0u;
    __syncthreads();

    float h_prev = 0.0f;

    int t = 0;
    while (t < len) {
        SCAN_STEP(0, exr, exz, exn)
        ++t;
        if (t >= len) break;
        SCAN_STEP(1, oxr, oxz, oxn)
        ++t;
    }

    if (!WRITE_SEQ && fq == 0)
        final_out[(size_t)b * H_DIM + jl] = h_prev;
}

extern "C" void kernel_launch(void* const* d_in, const int* in_sizes, int n_in,
                              void* d_out, int out_size, void* d_ws, size_t ws_size,
                              hipStream_t stream)
{
    (void)in_sizes; (void)n_in; (void)out_size; (void)ws_size;
    const float* x      = (const float*)d_in[0];
    const float* w_proj = (const float*)d_in[1];
    const float* b_proj = (const float*)d_in[2];
    const float* w_ih   = (const float*)d_in[3];
    const float* w_hh   = (const float*)d_in[4];
    const float* b_ih   = (const float*)d_in[5];
    const float* b_hh   = (const float*)d_in[6];
    float* out = (float*)d_out;

    // ws: [0,64MB) feat/out0 (f32); [64MB,+96MB) gx (f16); [256MB,+256B) lengths
    char*     ws      = (char*)d_ws;
    float*    feat    = (float*)(ws);
    _Float16* gxbuf   = (_Float16*)(ws + 67108864ull);
    int*      lengths = (int*)  (ws + 268435456ull);

    hipMemsetAsync(lengths, 0, B_DIM * sizeof(int), stream);

    const int M = B_DIM * T_DIM;
    // 1) feat = x @ w_proj^T + b_proj (+ lengths)   M=131072, N=128, K=512
    gemm_mfma_kernel<F_DIM, H_DIM, true, float>
        <<<dim3(M / 128, 1), 256, 0, stream>>>(x, w_proj, b_proj, feat, lengths);
    // 2) gx0 = feat @ w_ih[0]^T + b_ih[0]  (f16 out) M=131072, N=384, K=128
    gemm_mfma_kernel<H_DIM, G_DIM, false, _Float16>
        <<<dim3(M / 128, 3), 256, 0, stream>>>(feat, w_ih, b_ih, gxbuf, nullptr);
    // 3) layer-0 scan -> out0 (feat buffer)
    gru_scan_mfma_kernel<true><<<B_DIM, 512, 0, stream>>>(
        gxbuf, w_hh, b_hh, lengths, feat, nullptr);
    // 4) gx1 = out0 @ w_ih[1]^T + b_ih[1]  (f16 out)
    gemm_mfma_kernel<H_DIM, G_DIM, false, _Float16>
        <<<dim3(M / 128, 3), 256, 0, stream>>>(feat, w_ih + G_DIM * H_DIM, b_ih + G_DIM, gxbuf, nullptr);
    // 5) layer-1 scan -> final top-layer state
    gru_scan_mfma_kernel<false><<<B_DIM, 512, 0, stream>>>(
        gxbuf, w_hh + G_DIM * H_DIM, b_hh + G_DIM, lengths, nullptr, out);
}

// Round 24
// 2006.981 us; speedup vs baseline: 1.4375x; 1.0007x over previous
//
#include <hip/hip_runtime.h>

#define B_DIM 64
#define T_DIM 2048
#define F_DIM 512
#define H_DIM 128
#define G_DIM 384  // 3*H

typedef _Float16 half2_t __attribute__((ext_vector_type(2)));
typedef _Float16 f16x8   __attribute__((ext_vector_type(8)));
typedef unsigned int uint32;
typedef uint32 u32x4 __attribute__((ext_vector_type(4)));
typedef short bf16x8 __attribute__((ext_vector_type(8)));
typedef float f32x4  __attribute__((ext_vector_type(4)));

__device__ __forceinline__ float sigmoid_f(float x) {
    return __fdividef(1.0f, 1.0f + __expf(-x));
}
__device__ __forceinline__ float tanh_f(float x) {
    return __fdividef(2.0f, 1.0f + __expf(-2.0f * x)) - 1.0f;
}

__device__ __forceinline__ uint32 packf16(float a, float b) {
    half2_t p; p.x = (_Float16)a; p.y = (_Float16)b;
    return __builtin_bit_cast(uint32, p);
}

__device__ __forceinline__ uint32 pk_bf16(float lo, float hi) {
    uint32 r;
    asm("v_cvt_pk_bf16_f32 %0, %1, %2" : "=v"(r) : "v"(lo), "v"(hi));
    return r;
}

#define FAST_BARRIER()                                                            \
    __builtin_amdgcn_sched_barrier(0);                                            \
    asm volatile("s_waitcnt lgkmcnt(0)" ::: "memory");                            \
    __builtin_amdgcn_s_barrier();                                                 \
    __builtin_amdgcn_sched_barrier(0);

// ---------------------------------------------------------------------------
// bf16 MFMA GEMM (R10-proven): C[M x NDIM] = A @ W^T + bias (+bias2 for n<256);
// OUT_T = float (feat) or _Float16 (gx). lengths via per-wave ballot (R23).
// bias2 = b_hh of the consuming layer: its r/z components fold into gx
// legally (r = sigma(xr+bihr + hr+bhhr)); the n component must stay in the
// scan (inside r*(an+bhhn)).
// ---------------------------------------------------------------------------
template<int KDIM, int NDIM, bool DO_LEN, typename OUT_T>
__global__ __launch_bounds__(256)
void gemm_mfma_kernel(const float* __restrict__ A, const float* __restrict__ W,
                      const float* __restrict__ bias, OUT_T* __restrict__ C,
                      int* __restrict__ lengths, const float* __restrict__ bias2)
{
    constexpr int KSTEPS = KDIM / 32;
    constexpr int PAD = 40;
    __shared__ __align__(16) unsigned short At[128 * PAD];
    __shared__ __align__(16) unsigned short Bt[128 * PAD];

    const int tid = threadIdx.x;
    const int m0  = blockIdx.x * 128;
    const int n0  = blockIdx.y * 128;
    const int row = tid >> 1;
    const int kh  = tid & 1;

    const float* Ap = A + (size_t)(m0 + row) * KDIM + kh * 16;
    const float* Wp = W + (size_t)(n0 + row) * KDIM + kh * 16;

    float4 aPre[4], bPre[4];
#pragma unroll
    for (int q = 0; q < 4; ++q) {
        aPre[q] = *(const float4*)(Ap + q * 4);
        bPre[q] = *(const float4*)(Wp + q * 4);
    }

    f32x4 acc[4][4];
#pragma unroll
    for (int i = 0; i < 4; ++i)
#pragma unroll
        for (int j = 0; j < 4; ++j) acc[i][j] = (f32x4){0.f, 0.f, 0.f, 0.f};

    const int wv = tid >> 6;
    const int wm = (wv >> 1) * 64;
    const int wn = (wv & 1) * 64;
    const int ln = tid & 63;
    const int fr = ln & 15;
    const int fq = ln >> 4;

    float rowsum = 0.0f;

    for (int ks = 0; ks < KSTEPS; ++ks) {
        if (DO_LEN) {
#pragma unroll
            for (int q = 0; q < 4; ++q)
                rowsum += aPre[q].x + aPre[q].y + aPre[q].z + aPre[q].w;
        }
        {
            uint32* ad = (uint32*)&At[row * PAD + kh * 16];
            uint32* bd = (uint32*)&Bt[row * PAD + kh * 16];
            uint4 au, bu;
            au.x = pk_bf16(aPre[0].x, aPre[0].y); au.y = pk_bf16(aPre[0].z, aPre[0].w);
            au.z = pk_bf16(aPre[1].x, aPre[1].y); au.w = pk_bf16(aPre[1].z, aPre[1].w);
            *(uint4*)ad = au;
            au.x = pk_bf16(aPre[2].x, aPre[2].y); au.y = pk_bf16(aPre[2].z, aPre[2].w);
            au.z = pk_bf16(aPre[3].x, aPre[3].y); au.w = pk_bf16(aPre[3].z, aPre[3].w);
            *(uint4*)(ad + 4) = au;
            bu.x = pk_bf16(bPre[0].x, bPre[0].y); bu.y = pk_bf16(bPre[0].z, bPre[0].w);
            bu.z = pk_bf16(bPre[1].x, bPre[1].y); bu.w = pk_bf16(bPre[1].z, bPre[1].w);
            *(uint4*)bd = bu;
            bu.x = pk_bf16(bPre[2].x, bPre[2].y); bu.y = pk_bf16(bPre[2].z, bPre[2].w);
            bu.z = pk_bf16(bPre[3].x, bPre[3].y); bu.w = pk_bf16(bPre[3].z, bPre[3].w);
            *(uint4*)(bd + 4) = bu;
        }
        __syncthreads();
        if (ks + 1 < KSTEPS) {
#pragma unroll
            for (int q = 0; q < 4; ++q) {
                aPre[q] = *(const float4*)(Ap + (ks + 1) * 32 + q * 4);
                bPre[q] = *(const float4*)(Wp + (ks + 1) * 32 + q * 4);
            }
        }
        bf16x8 aF[4], bF[4];
#pragma unroll
        for (int i = 0; i < 4; ++i) {
            aF[i] = *(const bf16x8*)&At[(wm + i * 16 + fr) * PAD + fq * 8];
            bF[i] = *(const bf16x8*)&Bt[(wn + i * 16 + fr) * PAD + fq * 8];
        }
#pragma unroll
        for (int i = 0; i < 4; ++i)
#pragma unroll
            for (int j = 0; j < 4; ++j)
                acc[i][j] = __builtin_amdgcn_mfma_f32_16x16x32_bf16(
                                aF[i], bF[j], acc[i][j], 0, 0, 0);
        __syncthreads();
    }

#pragma unroll
    for (int i = 0; i < 4; ++i) {
#pragma unroll
        for (int j = 0; j < 4; ++j) {
            const int n = n0 + wn + j * 16 + fr;
            float bn = bias[n];
            if (bias2 && n < 256) bn += bias2[n];   // fold bhh r/z components
            const int mbase = m0 + wm + i * 16 + fq * 4;
#pragma unroll
            for (int r = 0; r < 4; ++r)
                C[(size_t)(mbase + r) * NDIM + n] = (OUT_T)(acc[i][j][r] + bn);
        }
    }

    if (DO_LEN && blockIdx.y == 0) {
        rowsum += __shfl_xor(rowsum, 1);
        unsigned long long m = __ballot(kh == 0 && rowsum != 0.0f);
        int cnt = __popcll(m);
        if (ln == 0 && cnt > 0)
            atomicAdd(&lengths[m0 >> 11], cnt);
    }
}

// ---------------------------------------------------------------------------
// Barrier-minimal MFMA GRU scan (R16-proven) with R24 chain surgery:
// per gate, 2 PARALLEL 2-deep MFMA chains + one f32 join (was one 4-deep
// chain): removes ~2 MFMA-latency hops from the serial step chain.
// gx carries bih + bhh(r,z) (folded in GEMM); scan keeps only bhn.
// ---------------------------------------------------------------------------
#define SCAN_STEP(PR, CXR, CXZ, CXN)                                              \
    {                                                                             \
        const _Float16* hb = (const _Float16*)&hbuf[PR][0];                       \
        f16x8 ha0 = *(const f16x8*)(hb + 0 * 32 + fq * 8);                        \
        f16x8 ha1 = *(const f16x8*)(hb + 1 * 32 + fq * 8);                        \
        f16x8 ha2 = *(const f16x8*)(hb + 2 * 32 + fq * 8);                        \
        f16x8 ha3 = *(const f16x8*)(hb + 3 * 32 + fq * 8);                        \
        f32x4 z4 = (f32x4){0.f,0.f,0.f,0.f};                                     \
        f32x4 r0 = __builtin_amdgcn_mfma_f32_16x16x32_f16(ha0, wR0, z4, 0,0,0);   \
        f32x4 z0 = __builtin_amdgcn_mfma_f32_16x16x32_f16(ha0, wZ0, z4, 0,0,0);   \
        f32x4 n0_ = __builtin_amdgcn_mfma_f32_16x16x32_f16(ha0, wN0, z4, 0,0,0);  \
        f32x4 r1 = __builtin_amdgcn_mfma_f32_16x16x32_f16(ha2, wR2, z4, 0,0,0);   \
        f32x4 z1 = __builtin_amdgcn_mfma_f32_16x16x32_f16(ha2, wZ2, z4, 0,0,0);   \
        f32x4 n1_ = __builtin_amdgcn_mfma_f32_16x16x32_f16(ha2, wN2, z4, 0,0,0);  \
        r0 = __builtin_amdgcn_mfma_f32_16x16x32_f16(ha1, wR1, r0, 0,0,0);         \
        z0 = __builtin_amdgcn_mfma_f32_16x16x32_f16(ha1, wZ1, z0, 0,0,0);         \
        n0_ = __builtin_amdgcn_mfma_f32_16x16x32_f16(ha1, wN1, n0_, 0,0,0);       \
        r1 = __builtin_amdgcn_mfma_f32_16x16x32_f16(ha3, wR3, r1, 0,0,0);         \
        z1 = __builtin_amdgcn_mfma_f32_16x16x32_f16(ha3, wZ3, z1, 0,0,0);         \
        n1_ = __builtin_amdgcn_mfma_f32_16x16x32_f16(ha3, wN3, n1_, 0,0,0);       \
        float ar = r0[0] + r1[0], az = z0[0] + z1[0], an = n0_[0] + n1_[0];       \
        int tp = t + 2; if (tp > T_DIM - 1) tp = T_DIM - 1;                       \
        const _Float16* gp = gxb + (size_t)tp * G_DIM + jl;                       \
        float nxr = (float)gp[0], nxz = (float)gp[128], nxn = (float)gp[256];     \
        float r  = sigmoid_f(CXR + ar);                                           \
        float z  = sigmoid_f(CXZ + az);                                           \
        float nn = tanh_f(CXN + r * (an + bhn));                                  \
        float hnew = nn + z * (h_prev - nn);                                      \
        h_prev = hnew;                                                            \
        if (fq == 0) {                                                            \
            ((_Float16*)&hbuf[PR ^ 1][0])[jl] = (_Float16)hnew;                   \
            if (WRITE_SEQ) seqb[(size_t)t * H_DIM + jl] = hnew;                   \
        }                                                                         \
        CXR = nxr; CXZ = nxz; CXN = nxn;                                          \
        FAST_BARRIER()                                                            \
    }

template<bool WRITE_SEQ>
__global__ __attribute__((amdgpu_flat_work_group_size(512, 512),
                          amdgpu_waves_per_eu(2, 2)))
void gru_scan_mfma_kernel(const _Float16* __restrict__ gx,  // [B,T,3H] f16 (bih+bhh_rz)
                          const float* __restrict__ whh,    // [3H,H] this layer
                          const float* __restrict__ bhh,    // [3H] (only n used)
                          const int*   __restrict__ lengths,
                          float* __restrict__ seq_out,      // [B,T,H] if WRITE_SEQ
                          float* __restrict__ final_out)    // [B,H]  if !WRITE_SEQ
{
    __shared__ __align__(16) uint32 hbuf[2][68];

    const int b   = blockIdx.x;
    const int tid = threadIdx.x;
    const int w   = tid >> 6;
    const int ln  = tid & 63;
    const int fr  = ln & 15;
    const int fq  = ln >> 4;
    const int jl  = w * 16 + fr;

    f16x8 wR0, wR1, wR2, wR3, wZ0, wZ1, wZ2, wZ3, wN0, wN1, wN2, wN3;
    {
        const float* base = whh + (size_t)jl * H_DIM + fq * 8;
#define LOADW(dst, g, c)                                                          \
        {                                                                         \
            const float* wp = base + (size_t)(g) * 128 * H_DIM + (c) * 32;        \
            float4 v0 = *(const float4*)wp;                                       \
            float4 v1 = *(const float4*)(wp + 4);                                 \
            u32x4 u;                                                              \
            u.x = packf16(v0.x, v0.y); u.y = packf16(v0.z, v0.w);                 \
            u.z = packf16(v1.x, v1.y); u.w = packf16(v1.z, v1.w);                 \
            dst = __builtin_bit_cast(f16x8, u);                                   \
        }
        LOADW(wR0, 0, 0) LOADW(wR1, 0, 1) LOADW(wR2, 0, 2) LOADW(wR3, 0, 3)
        LOADW(wZ0, 1, 0) LOADW(wZ1, 1, 1) LOADW(wZ2, 1, 2) LOADW(wZ3, 1, 3)
        LOADW(wN0, 2, 0) LOADW(wN1, 2, 1) LOADW(wN2, 2, 2) LOADW(wN3, 2, 3)
#undef LOADW
    }

    const int len = lengths[b];
    const _Float16* gxb = gx + (size_t)b * T_DIM * G_DIM;
    float* seqb = WRITE_SEQ ? (seq_out + (size_t)b * T_DIM * H_DIM) : nullptr;

    const float bhn = bhh[jl + 256];   // only the n-gate bhh stays in the scan

    float exr = (float)gxb[jl],         exz = (float)gxb[jl + 128];
    float exn = (float)gxb[jl + 256];
    float oxr = (float)gxb[G_DIM + jl], oxz = (float)gxb[G_DIM + jl + 128];
    float oxn = (float)gxb[G_DIM + jl + 256];

    for (int i = tid; i < 2 * 68; i += 512) ((uint32*)hbuf)[i] = 0u;
    __syncthreads();

    float h_prev = 0.0f;

    int t = 0;
    while (t < len) {
        SCAN_STEP(0, exr, exz, exn)
        ++t;
        if (t >= len) break;
        SCAN_STEP(1, oxr, oxz, oxn)
        ++t;
    }

    if (!WRITE_SEQ && fq == 0)
        final_out[(size_t)b * H_DIM + jl] = h_prev;
}

extern "C" void kernel_launch(void* const* d_in, const int* in_sizes, int n_in,
                              void* d_out, int out_size, void* d_ws, size_t ws_size,
                              hipStream_t stream)
{
    (void)in_sizes; (void)n_in; (void)out_size; (void)ws_size;
    const float* x      = (const float*)d_in[0];
    const float* w_proj = (const float*)d_in[1];
    const float* b_proj = (const float*)d_in[2];
    const float* w_ih   = (const float*)d_in[3];
    const float* w_hh   = (const float*)d_in[4];
    const float* b_ih   = (const float*)d_in[5];
    const float* b_hh   = (const float*)d_in[6];
    float* out = (float*)d_out;

    // ws: [0,64MB) feat/out0 (f32); [64MB,+96MB) gx (f16); [256MB,+256B) lengths
    char*     ws      = (char*)d_ws;
    float*    feat    = (float*)(ws);
    _Float16* gxbuf   = (_Float16*)(ws + 67108864ull);
    int*      lengths = (int*)  (ws + 268435456ull);

    hipMemsetAsync(lengths, 0, B_DIM * sizeof(int), stream);

    const int M = B_DIM * T_DIM;
    // 1) feat = x @ w_proj^T + b_proj (+ lengths)   M=131072, N=128, K=512
    gemm_mfma_kernel<F_DIM, H_DIM, true, float>
        <<<dim3(M / 128, 1), 256, 0, stream>>>(x, w_proj, b_proj, feat, lengths, nullptr);
    // 2) gx0 = feat @ w_ih[0]^T + b_ih[0] + bhh0(r,z)  (f16 out)
    gemm_mfma_kernel<H_DIM, G_DIM, false, _Float16>
        <<<dim3(M / 128, 3), 256, 0, stream>>>(feat, w_ih, b_ih, gxbuf, nullptr, b_hh);
    // 3) layer-0 scan -> out0 (feat buffer)
    gru_scan_mfma_kernel<true><<<B_DIM, 512, 0, stream>>>(
        gxbuf, w_hh, b_hh, lengths, feat, nullptr);
    // 4) gx1 = out0 @ w_ih[1]^T + b_ih[1] + bhh1(r,z)  (f16 out)
    gemm_mfma_kernel<H_DIM, G_DIM, false, _Float16>
        <<<dim3(M / 128, 3), 256, 0, stream>>>(feat, w_ih + G_DIM * H_DIM,
                                               b_ih + G_DIM, gxbuf, nullptr, b_hh + G_DIM);
    // 5) layer-1 scan -> final top-layer state
    gru_scan_mfma_kernel<false><<<B_DIM, 512, 0, stream>>>(
        gxbuf, w_hh + G_DIM * H_DIM, b_hh + G_DIM, lengths, nullptr, out);
}